// Round 12
// baseline (322.545 us; speedup 1.0000x reference)
//
#include <hip/hip_runtime.h>

// LSTM: B=8192, T=512, H=32. Block = 512 threads (8 waves) owning 32 batches
// (two 16-batch groups A,B); 256 blocks -> 1 block/CU, 8 waves/CU (2/SIMD).
// SOFTWARE-PIPELINED: each barrier interval = MFMA-phase of one group +
// cell-phase of the other (acc carried in registers across the barrier), so
// the ds_read+MFMA chain of X overlaps the exp2/rcp chain of Y in the SAME
// wave. Chain per interval = max(parts), not sum (R8 failed because it
// shared phases -> sum). 2 intervals = 1 timestep for both groups.
// Transposed MFMA D = W'*h via mfma_f32_16x16x32_f16, wave w owns tile w:
// row m=c -> (gate c&3, unit 8*(c>>2)+w); C/D: lane (c,q) reg r = gate r of
// cell (unit 8q+w, batch c) -> 1 cell/lane/group. fp16 2-term scheme
// (weights single fp16, h hi/lo split, 2 chained MFMAs; absmax ~1e-3 ✓ R11).
// K-perm j^2q keeps h-plane access 2-way bank-aliased. Single-buffer h
// planes per group (read@k, rewrite@k+2). Gates pre-scaled by -log2e /
// +2log2e; cell = 5 exp2 + 2 rcp (exact identities).

#define TT 512
#define HH 32
#define L2E 1.44269504088896340736f

typedef _Float16 f16x8 __attribute__((ext_vector_type(8)));
typedef float f32x4 __attribute__((ext_vector_type(4)));

__device__ __forceinline__ float fastrcp(float x) { return __builtin_amdgcn_rcpf(x); }
__device__ __forceinline__ float exp2f_(float x) { return __builtin_amdgcn_exp2f(x); }

#define XROW 132   // x tile row stride (floats): bank (4c+t) mod 32 -> 2-way

__launch_bounds__(512)
__global__ void lstm_kernel(const float* __restrict__ x,
                            const float* __restrict__ W_ih,
                            const float* __restrict__ W_hh,
                            const float* __restrict__ b_ih,
                            const float* __restrict__ b_hh,
                            const float* __restrict__ W_fc,
                            const float* __restrict__ b_fc,
                            float* __restrict__ out) {
    // h planes: [group][qblk(4)][batch(16)][j(8)] fp16 (single-buffered)
    __shared__ _Float16 hh[2][512];
    __shared__ _Float16 hl[2][512];
    // x tiles: [buf][group][batch][t mod 128] (double-buffered, 1-tile lookahead)
    __shared__ float xbuf[2][2][16 * XROW];

    const int tid  = threadIdx.x;
    const int lane = tid & 63;
    const int w    = tid >> 6;        // wave id 0..7: owns tile w
    const int c    = lane & 15;       // batch-in-group (MFMA n); also A m-row
    const int q    = lane >> 4;       // quad: k-block 8q; unit-block 8q
    const int base = blockIdx.x * 32; // 32 batches = groups A (0..15), B (16..31)

    // ---- A-fragment (weights), tile w, single fp16, k-perm j^2q ----
    const int gate = c & 3;
    const float asc = (gate == 2) ? (2.0f * L2E) : (-L2E);
    const int arow = gate * 32 + 8 * (c >> 2) + w;
    f16x8 wah;
    #pragma unroll
    for (int j = 0; j < 8; ++j) {
        const int u = 8 * q + (j ^ (2 * q));
        wah[j] = (_Float16)(W_hh[arow * HH + u] * asc);
    }

    // ---- cell consts: this lane's cell unit u = 8q + w (both groups) ----
    const int uu = 8 * q + w;
    f32x4 wihs, bcs;
    #pragma unroll
    for (int r = 0; r < 4; ++r) {
        const float sc = (r == 2) ? (2.0f * L2E) : (-L2E);
        wihs[r] = W_ih[32 * r + uu] * sc;
        bcs[r]  = (b_ih[32 * r + uu] + b_hh[32 * r + uu]) * sc;
    }

    // ---- init h planes to zero (h0 = 0), both groups ----
    hh[0][tid] = (_Float16)0.f; hl[0][tid] = (_Float16)0.f;
    hh[1][tid] = (_Float16)0.f; hl[1][tid] = (_Float16)0.f;

    float csA = 0.f, csB = 0.f;

    // ---- prime: accB = gates_B(0) = Cinit(x_B(0)) (h0 = 0 -> no MFMA term)
    const float xB0 = x[(base + 16 + c) * TT + 0];
    f32x4 accB = wihs * xB0 + bcs;
    f32x4 accA;

    const int rdo = q * 128 + c * 8;          // B-frag read offset (fp16)
    const int wro = rdo + (w ^ (2 * q));      // h write offset (b16, 2-way)

    // x staging indices: per tile: 2 groups x 16 rows x 128 floats
    const int xrow = tid >> 5;                // 0..15
    const int xj4  = (tid & 31) * 4;          // 0..124

    // scalar cell update: acc (4 pre-scaled gates) + cs -> h, cs updated
    #define CELL(ACC, CS, H)                                                  \
        {                                                                     \
            const float Ei = exp2f_(ACC[0]);                                  \
            const float Ef = exp2f_(ACC[1]);                                  \
            const float G  = exp2f_(ACC[2]);                                  \
            const float Eo = exp2f_(ACC[3]);                                  \
            const float aig = (1.f + Ei) * (G + 1.f);                         \
            const float af  = 1.f + Ef;                                       \
            const float cn  = (CS * aig + (G - 1.f) * af) * fastrcp(af * aig);\
            CS = cn;                                                          \
            float yc = cn * (2.0f * L2E);                                     \
            yc = fminf(60.f, fmaxf(-60.f, yc));                               \
            const float C = exp2f_(yc);                                       \
            H = (C - 1.f) * fastrcp((C + 1.f) * (1.f + Eo));                  \
        }

    for (int m = 0; m < TT; ++m) {
        // ---- stage x tiles (tile k covers t in [128k, 128k+128)) ----
        if ((m & 127) == 0) {
            const int kt = m >> 7;
            if (kt == 0) {           // prologue: stage tiles 0 and 1
                #pragma unroll
                for (int k = 0; k < 2; ++k) {
                    #pragma unroll
                    for (int g = 0; g < 2; ++g) {
                        const float4 v = *(const float4*)
                            &x[(base + g * 16 + xrow) * TT + 128 * k + xj4];
                        *(float4*)&xbuf[k][g][xrow * XROW + xj4] = v;
                    }
                }
            } else if (kt < 3) {     // stage lookahead tile kt+1
                #pragma unroll
                for (int g = 0; g < 2; ++g) {
                    const float4 v = *(const float4*)
                        &x[(base + g * 16 + xrow) * TT + 128 * (kt + 1) + xj4];
                    *(float4*)&xbuf[(kt + 1) & 1][g][xrow * XROW + xj4] = v;
                }
            }
            __syncthreads();
        }

        // ======== even interval: MFMA_A(m) ; cell_B(gates_B(m)) ========
        {
            const f16x8 bhA = *(const f16x8*)&hh[0][rdo];   // h_A(m) hi
            const f16x8 blA = *(const f16x8*)&hl[0][rdo];   // h_A(m) lo
            const float xA  = xbuf[(m >> 7) & 1][0][c * XROW + (m & 127)];

            // cell-phase for B (register-only; overlaps the ds_read latency)
            float hB;
            CELL(accB, csB, hB);
            const _Float16 hB16 = (_Float16)hB;
            hh[1][wro] = hB16;
            hl[1][wro] = (_Float16)(hB - (float)hB16);

            f32x4 ci = wihs * xA + bcs;
            ci = __builtin_amdgcn_mfma_f32_16x16x32_f16(wah, blA, ci, 0, 0, 0);
            accA = __builtin_amdgcn_mfma_f32_16x16x32_f16(wah, bhA, ci, 0, 0, 0);
        }
        __syncthreads();

        // ======== odd interval: MFMA_B(m+1) ; cell_A(gates_A(m)) ========
        {
            const f16x8 bhB = *(const f16x8*)&hh[1][rdo];   // h_B(m+1) hi
            const f16x8 blB = *(const f16x8*)&hl[1][rdo];   // h_B(m+1) lo
            const int tn = (m + 1 < TT) ? (m + 1) : (TT - 1); // clamped (unused at m=511)
            const float xB = xbuf[(tn >> 7) & 1][1][c * XROW + (tn & 127)];

            float hA;
            CELL(accA, csA, hA);
            const _Float16 hA16 = (_Float16)hA;
            hh[0][wro] = hA16;
            hl[0][wro] = (_Float16)(hA - (float)hA16);

            f32x4 ci = wihs * xB + bcs;
            ci = __builtin_amdgcn_mfma_f32_16x16x32_f16(wah, blB, ci, 0, 0, 0);
            accB = __builtin_amdgcn_mfma_f32_16x16x32_f16(wah, bhB, ci, 0, 0, 0);
        }
        __syncthreads();
    }
    // After m=511: h_A(512) and h_B(512) are in the planes; barrier passed.

    // ---- head: out[b] = h_T @ W_fc^T + b_fc (k-perm aware) ----
    if (tid < 32) {
        const int g  = tid >> 4;
        const int bb = tid & 15;
        float s = b_fc[0];
        #pragma unroll
        for (int u = 0; u < 32; ++u) {
            const int off = (u >> 3) * 128 + bb * 8 + ((u & 7) ^ (2 * (u >> 3)));
            s += ((float)hh[g][off] + (float)hl[g][off]) * W_fc[u];
        }
        out[base + g * 16 + bb] = s;
    }
}

extern "C" void kernel_launch(void* const* d_in, const int* in_sizes, int n_in,
                              void* d_out, int out_size, void* d_ws, size_t ws_size,
                              hipStream_t stream) {
    const float* x    = (const float*)d_in[0];
    const float* W_ih = (const float*)d_in[1];
    const float* W_hh = (const float*)d_in[2];
    const float* b_ih = (const float*)d_in[3];
    const float* b_hh = (const float*)d_in[4];
    const float* W_fc = (const float*)d_in[5];
    const float* b_fc = (const float*)d_in[6];
    float* out = (float*)d_out;

    const int B = 8192;
    lstm_kernel<<<B / 32, 512, 0, stream>>>(x, W_ih, W_hh, b_ih, b_hh,
                                            W_fc, b_fc, out);
}